// Round 8
// baseline (32.305 us; speedup 1.0000x reference)
//
#include <hip/hip_runtime.h>

// EnergyPool2d: N=16, C=64, H=W=128, 3x3 windows stride 1 -> Ho=Wo=126.
// +1 at first-argmax flat index, -1 at first-argmin flat index per window.
// R8: half-plane blocks (512 thr, 32KB LDS count) for 2x scheduling
// granularity: 2048 blocks, 4 resident/CU (100% wave ceiling), 8 blocks/CU
// of work. Halves overlap on window rows 62-63; each LDS add is guarded by
// the ownership test 0 <= flat - half*8192 < 8192 (no global atomics).

#define HH 128
#define WW 128
#define HO 126
#define WO 126
#define PLANE (HH * WW)     // 16384
#define HROWS 64
#define HPLANE (HROWS * WW) // 8192
#define NPLANES (16 * 64)   // 1024
#define BLOCK 512

// First-occurrence argmax/argmin over a 3x3 window, row-major scan order
// (strict > / <). base = plane-flat index of window top-left; bias = LDS
// region start. Adds only land in this block's half (guard = ownership).
__device__ __forceinline__ void scan9(float w0, float w1, float w2,
                                      float w3, float w4, float w5,
                                      float w6, float w7, float w8,
                                      int base, int bias, int* __restrict__ cnt) {
    float vmax = w0, vmin = w0;
    int omax = 0, omin = 0;
#define STEP(v, off)                                      \
    do {                                                  \
        if ((v) > vmax) { vmax = (v); omax = (off); }     \
        if ((v) < vmin) { vmin = (v); omin = (off); }     \
    } while (0)
    STEP(w1, 1);
    STEP(w2, 2);
    STEP(w3, WW);
    STEP(w4, WW + 1);
    STEP(w5, WW + 2);
    STEP(w6, 2 * WW);
    STEP(w7, 2 * WW + 1);
    STEP(w8, 2 * WW + 2);
#undef STEP
    const int iM = base + omax - bias;
    if ((unsigned)iM < HPLANE) atomicAdd(&cnt[iM], 1);
    const int im = base + omin - bias;
    if ((unsigned)im < HPLANE) atomicAdd(&cnt[im], -1);
}

__global__ __launch_bounds__(BLOCK, 8)
void energy_pool2d_kernel(const float* __restrict__ x, float* __restrict__ out) {
    __shared__ int cnt[HPLANE]; // 32 KB

    const int tid = threadIdx.x;
    const int plane = blockIdx.x >> 1;
    const int half = blockIdx.x & 1;
    const float* __restrict__ xp = x + (size_t)plane * PLANE;

    // Zero the LDS half-plane.
    int4* c4 = (int4*)cnt;
#pragma unroll
    for (int i = 0; i < HPLANE / 4 / BLOCK; ++i)
        c4[tid + i * BLOCK] = make_int4(0, 0, 0, 0);
    __syncthreads();

    const int row0 = half ? 62 : 0;   // first window row for this half
    const int bias = half * HPLANE;

    // 1024 tiles per half (32 row-tiles x 32 col-tiles), 2 per thread.
#pragma unroll
    for (int it = 0; it < 2; ++it) {
        const int t = tid + it * BLOCK;
        const int rt = t >> 5;        // 0..31
        const int ct = t & 31;        // 0..31
        const int wr0 = row0 + rt * 2; // window rows wr0, wr0+1
        const int j0 = ct * 4;
        const float* __restrict__ p = xp + wr0 * WW + j0;

        // 4 input rows x 8 cols; right float4 skipped at right edge
        // (ct=31 -> windows at cols 124,125 only; keeps loads in-bounds).
        const float4 a0 = *(const float4*)(p);
        const float4 a1 = *(const float4*)(p + WW);
        const float4 a2 = *(const float4*)(p + 2 * WW);
        const float4 a3 = *(const float4*)(p + 3 * WW);
        float4 b0, b1, b2, b3;
        if (ct < 31) {
            b0 = *(const float4*)(p + 4);
            b1 = *(const float4*)(p + WW + 4);
            b2 = *(const float4*)(p + 2 * WW + 4);
            b3 = *(const float4*)(p + 3 * WW + 4);
        } else {
            b0 = b1 = b2 = b3 = make_float4(0.f, 0.f, 0.f, 0.f);
        }
        const float r0[8] = {a0.x, a0.y, a0.z, a0.w, b0.x, b0.y, b0.z, b0.w};
        const float r1[8] = {a1.x, a1.y, a1.z, a1.w, b1.x, b1.y, b1.z, b1.w};
        const float r2[8] = {a2.x, a2.y, a2.z, a2.w, b2.x, b2.y, b2.z, b2.w};
        const float r3[8] = {a3.x, a3.y, a3.z, a3.w, b3.x, b3.y, b3.z, b3.w};

        const int nw = (ct < 31) ? 4 : 2;
        const int base0 = wr0 * WW + j0;
#pragma unroll
        for (int c = 0; c < 4; ++c) {
            if (c < nw) {
                scan9(r0[c], r0[c + 1], r0[c + 2],
                      r1[c], r1[c + 1], r1[c + 2],
                      r2[c], r2[c + 1], r2[c + 2], base0 + c, bias, cnt);
                scan9(r1[c], r1[c + 1], r1[c + 2],
                      r2[c], r2[c + 1], r2[c + 2],
                      r3[c], r3[c + 1], r3[c + 2], base0 + WW + c, bias, cnt);
            }
        }
    }
    __syncthreads();

    // Coalesced writeout of this half (fully overwritten -> no pre-zero).
    float4* __restrict__ o4 = (float4*)(out + (size_t)plane * PLANE + bias);
#pragma unroll
    for (int i = 0; i < HPLANE / 4 / BLOCK; ++i) {
        const int4 ci = c4[tid + i * BLOCK];
        o4[tid + i * BLOCK] =
            make_float4((float)ci.x, (float)ci.y, (float)ci.z, (float)ci.w);
    }
}

extern "C" void kernel_launch(void* const* d_in, const int* in_sizes, int n_in,
                              void* d_out, int out_size, void* d_ws, size_t ws_size,
                              hipStream_t stream) {
    const float* x = (const float*)d_in[0];
    float* out = (float*)d_out;
    energy_pool2d_kernel<<<NPLANES * 2, BLOCK, 0, stream>>>(x, out);
}